// Round 3
// baseline (147.113 us; speedup 1.0000x reference)
//
#include <hip/hip_runtime.h>

#define BATCH 8
#define CIN   64
#define COUT  64
#define Hdim  128
#define Wdim  128
#define HW    (Hdim * Wdim)

typedef unsigned short ushort_t;
typedef unsigned short ushort8 __attribute__((ext_vector_type(8)));
typedef short short8 __attribute__((ext_vector_type(8)));
typedef unsigned int u32x4 __attribute__((ext_vector_type(4)));
typedef float f32x2 __attribute__((ext_vector_type(2)));
typedef float f32x4 __attribute__((ext_vector_type(4)));

__device__ __forceinline__ ushort_t f2b(float f) {
    unsigned int u = __float_as_uint(f);
    return (ushort_t)((u + 0x8000u) >> 16);
}
__device__ __forceinline__ f32x2 unpk(unsigned int u) {
    f32x2 v;
    v.x = __uint_as_float(u << 16);
    v.y = __uint_as_float(u & 0xffff0000u);
    return v;
}
__device__ __forceinline__ unsigned int pack2(f32x2 v) {
    unsigned int lo = (__float_as_uint(v.x) + 0x8000u) >> 16;
    unsigned int hi = (__float_as_uint(v.y) + 0x8000u) & 0xffff0000u;
    return lo | hi;
}

// ---------------- prep: x (B,C,H,W) f32 -> xt (B,H,W,C) bf16 ; w (O,C,3,3) f32 -> wt (9,O,C) bf16
__global__ __launch_bounds__(256) void dcnv2_prep(
    const float* __restrict__ x, const float* __restrict__ w,
    ushort_t* __restrict__ xt, ushort_t* __restrict__ wt)
{
    int bid = blockIdx.x;
    if (bid < 4096) {
        int g = bid * 256 + threadIdx.x;          // B*HW*8 = 1,048,576
        int pixel = g >> 3;
        int c0 = (g & 7) << 3;
        int b = pixel >> 14, hw = pixel & (HW - 1);
        const float* xp = x + (size_t)(b * CIN + c0) * HW + hw;
        ushort8 o;
#pragma unroll
        for (int i = 0; i < 8; ++i) o[i] = f2b(xp[(size_t)i * HW]);
        *(ushort8*)(xt + (size_t)pixel * 64 + c0) = o;
    } else {
        int t2 = (bid - 4096) * 256 + threadIdx.x; // 0..4095
        int o = t2 >> 6, c = t2 & 63;
        const float* wp = w + (size_t)(o * 64 + c) * 9;
#pragma unroll
        for (int k = 0; k < 9; ++k) wt[k * 4096 + o * 64 + c] = f2b(wp[k]);
    }
}

// ---------------- main: fused deformable-im2col + bf16 MFMA GEMM
// 256 thr (4 waves), 64 px/block. Sampling: lane = pixel, wave = 16-ch slice.
// MFMA: wave wv owns pixel rows [wv*16,+16), all 64 outs. col double-buffered,
// XOR-chunk-swizzled (row stride 128B), ONE barrier per tap.
__global__ __launch_bounds__(256) void dcnv2_mfma(
    const ushort_t* __restrict__ xt,   // (B,H,W,C) bf16
    const ushort_t* __restrict__ wt,   // (9,O,C) bf16
    const float* __restrict__ off,     // (B,18,H,W)
    const float* __restrict__ msk,     // (B,9,H,W)
    const float* __restrict__ bias,    // (O)
    float* __restrict__ out)           // (B,O,H,W)
{
    __shared__ ushort_t col[2][64 * 64];   // 2 x 8KB, chunk-swizzled

    int bid = blockIdx.x;
    int swz = (bid & 7) * 256 + (bid >> 3);   // XCD swizzle (2048 % 8 == 0)
    int tid = threadIdx.x;
    int pbase = swz << 6;

    int lane = tid & 63;
    int wv = tid >> 6;

    // ---- sampling mapping: lane = pixel row, wave = channel slice
    int p  = lane;                // tile row 0..63
    int c0 = wv << 4;             // channels wv*16 .. +15
    int q  = p & 7;               // swizzle key
    int pixel = pbase + p;
    int bb = pixel >> 14;
    int hw = pixel & (HW - 1);
    int y = hw >> 7, xq = hw & (Wdim - 1);

    const float* offb = off + (size_t)(bb * 18) * HW + hw;
    const float* mb   = msk + (size_t)(bb * 9) * HW + hw;
    const ushort_t* xtb = xt + (((size_t)bb << 14) << 6);

    // ---- mfma mapping
    int arow = (wv << 4) + (lane & 15);
    int asw  = arow & 7;
    int hi4  = lane >> 4;                       // 0..3
    const ushort_t* wtl = wt + (lane & 15) * 64 + (hi4 << 3);  // + k*4096 + n*1024 + s*32

    f32x4 acc[4];
#pragma unroll
    for (int n = 0; n < 4; ++n) acc[n] = (f32x4){0.f, 0.f, 0.f, 0.f};

#pragma unroll
    for (int k = 0; k < 9; ++k) {
        const int ky = k / 3, kx = k % 3;

        // ---- per-tap offset/mask (coalesced across lanes)
        float oyk = offb[(size_t)(2 * k) * HW];
        float oxk = offb[(size_t)(2 * k + 1) * HW];
        float mk  = mb[(size_t)k * HW];

        float py = (float)(y - 1 + ky) + oyk;
        float px = (float)(xq - 1 + kx) + oxk;
        float fy = floorf(py), fx = floorf(px);
        float ly = py - fy, lx = px - fx;
        float hy = 1.f - ly, hx = 1.f - lx;
        int y0 = (int)fy, x0 = (int)fx;
        int y1 = y0 + 1, x1 = x0 + 1;
        float vy0 = (y0 >= 0 && y0 < Hdim) ? mk : 0.f;
        float vy1 = (y1 >= 0 && y1 < Hdim) ? mk : 0.f;
        float vx0 = (x0 >= 0 && x0 < Wdim) ? 1.f : 0.f;
        float vx1 = (x1 >= 0 && x1 < Wdim) ? 1.f : 0.f;
        float w00 = hy * hx * vy0 * vx0, w01 = hy * lx * vy0 * vx1;
        float w10 = ly * hx * vy1 * vx0, w11 = ly * lx * vy1 * vx1;
        int cy0 = min(max(y0, 0), Hdim - 1), cy1 = min(max(y1, 0), Hdim - 1);
        int cx0 = min(max(x0, 0), Wdim - 1), cx1 = min(max(x1, 0), Wdim - 1);

        const ushort_t* p00 = xtb + (((cy0 << 7) + cx0) << 6) + c0;
        const ushort_t* p01 = xtb + (((cy0 << 7) + cx1) << 6) + c0;
        const ushort_t* p10 = xtb + (((cy1 << 7) + cx0) << 6) + c0;
        const ushort_t* p11 = xtb + (((cy1 << 7) + cx1) << 6) + c0;
        u32x4 a00 = *(const u32x4*)p00, b00 = *(const u32x4*)(p00 + 8);
        u32x4 a01 = *(const u32x4*)p01, b01 = *(const u32x4*)(p01 + 8);
        u32x4 a10 = *(const u32x4*)p10, b10 = *(const u32x4*)(p10 + 8);
        u32x4 a11 = *(const u32x4*)p11, b11 = *(const u32x4*)(p11 + 8);

        u32x4 olo, ohi;
#pragma unroll
        for (int i = 0; i < 4; ++i) {
            f32x2 v = unpk(a00[i]) * w00;
            v += unpk(a01[i]) * w01;
            v += unpk(a10[i]) * w10;
            v += unpk(a11[i]) * w11;
            olo[i] = pack2(v);
            f32x2 u = unpk(b00[i]) * w00;
            u += unpk(b01[i]) * w01;
            u += unpk(b10[i]) * w10;
            u += unpk(b11[i]) * w11;
            ohi[i] = pack2(u);
        }

        ushort_t* cbw = &col[k & 1][p << 6];
        *(u32x4*)(cbw + ((((wv << 1))     ^ q) << 3)) = olo;
        *(u32x4*)(cbw + ((((wv << 1) | 1) ^ q) << 3)) = ohi;

        __syncthreads();

        // ---- MFMA: K=64 for this tap; B-frags direct from global (L1/L2-hit)
        const ushort_t* cbr = &col[k & 1][0];
        const ushort_t* wtk = wtl + k * 4096;
#pragma unroll
        for (int s = 0; s < 2; ++s) {
            int ch = ((s << 2) + hi4) ^ asw;
            short8 af = *(const short8*)(cbr + (arow << 6) + (ch << 3));
#pragma unroll
            for (int n = 0; n < 4; ++n) {
                short8 bf = *(const short8*)(wtk + n * 1024 + s * 32);
                acc[n] = __builtin_amdgcn_mfma_f32_16x16x32_bf16(af, bf, acc[n], 0, 0, 0);
            }
        }
    }

    // ---- epilogue: D row = pixel (lane>>4)*4+j, col = out (lane&15)
    int hwb = pbase & (HW - 1);
    float* ob = out + ((size_t)bb << 6) * HW;
#pragma unroll
    for (int n = 0; n < 4; ++n) {
        int o = n * 16 + (lane & 15);
        float bv = bias[o];
#pragma unroll
        for (int j = 0; j < 4; ++j) {
            int ploc = (wv << 4) + ((lane >> 4) << 2) + j;
            ob[((size_t)o << 14) + hwb + ploc] = acc[n][j] + bv;
        }
    }
}

// ---------------- fallback (direct fp32 kernel) if ws too small
__global__ __launch_bounds__(256) void dcnv2_direct(
    const float* __restrict__ x, const float* __restrict__ off,
    const float* __restrict__ msk, const float* __restrict__ wgt,
    const float* __restrict__ bias, float* __restrict__ out)
{
    int pg = blockIdx.x * 256 + threadIdx.x;
    int b = pg >> 14;
    int hw = pg & (HW - 1);
    int y = hw >> 7;
    int xq = hw & (Wdim - 1);
    float acc[COUT];
#pragma unroll
    for (int o = 0; o < COUT; ++o) acc[o] = 0.0f;
    const float* xb = x + b * CIN * HW;
    const float* offb = off + b * 18 * HW + hw;
    const float* mb = msk + b * 9 * HW + hw;
    for (int k = 0; k < 9; ++k) {
        int ky = k / 3, kx = k % 3;
        float py = (float)(y - 1 + ky) + offb[(2 * k) * HW];
        float px = (float)(xq - 1 + kx) + offb[(2 * k + 1) * HW];
        float m = mb[k * HW];
        float fy = floorf(py), fx = floorf(px);
        float ly = py - fy, lx = px - fx;
        float hy = 1.0f - ly, hx = 1.0f - lx;
        int y0 = (int)fy, x0 = (int)fx;
        int y1 = y0 + 1, x1 = x0 + 1;
        float vy0 = (y0 >= 0 && y0 < Hdim) ? 1.f : 0.f;
        float vy1 = (y1 >= 0 && y1 < Hdim) ? 1.f : 0.f;
        float vx0 = (x0 >= 0 && x0 < Wdim) ? 1.f : 0.f;
        float vx1 = (x1 >= 0 && x1 < Wdim) ? 1.f : 0.f;
        float w00 = hy * hx * vy0 * vx0 * m, w01 = hy * lx * vy0 * vx1 * m;
        float w10 = ly * hx * vy1 * vx0 * m, w11 = ly * lx * vy1 * vx1 * m;
        int cy0 = min(max(y0, 0), Hdim - 1), cy1 = min(max(y1, 0), Hdim - 1);
        int cx0 = min(max(x0, 0), Wdim - 1), cx1 = min(max(x1, 0), Wdim - 1);
        int i00 = cy0 * Wdim + cx0, i01 = cy0 * Wdim + cx1;
        int i10 = cy1 * Wdim + cx0, i11 = cy1 * Wdim + cx1;
        const float* wk = wgt + k;
        const float* xc = xb;
        for (int c = 0; c < CIN; ++c) {
            float val = w00 * xc[i00] + w01 * xc[i01] + w10 * xc[i10] + w11 * xc[i11];
            const float* wc = wk + c * 9;
#pragma unroll
            for (int o = 0; o < COUT; ++o)
                acc[o] = fmaf(wc[o * (CIN * 9)], val, acc[o]);
            xc += HW;
        }
    }
    float* op = out + b * COUT * HW + hw;
#pragma unroll
    for (int o = 0; o < COUT; ++o) op[o * HW] = acc[o] + bias[o];
}

extern "C" void kernel_launch(void* const* d_in, const int* in_sizes, int n_in,
                              void* d_out, int out_size, void* d_ws, size_t ws_size,
                              hipStream_t stream) {
    const float* x    = (const float*)d_in[0];
    const float* off  = (const float*)d_in[1];
    const float* msk  = (const float*)d_in[2];
    const float* wgt  = (const float*)d_in[3];
    const float* bias = (const float*)d_in[4];
    float* out = (float*)d_out;

    const size_t xt_elems = (size_t)BATCH * HW * 64;   // 8,388,608 bf16
    const size_t wt_elems = 9 * 4096;                  // 36,864 bf16
    const size_t need = (xt_elems + wt_elems) * sizeof(ushort_t);

    if (ws_size < need) {
        dcnv2_direct<<<(BATCH * HW) / 256, 256, 0, stream>>>(x, off, msk, wgt, bias, out);
        return;
    }

    ushort_t* xt = (ushort_t*)d_ws;
    ushort_t* wt = xt + xt_elems;

    dcnv2_prep<<<4096 + 16, 256, 0, stream>>>(x, wgt, xt, wt);
    dcnv2_mfma<<<2048, 256, 0, stream>>>(xt, wt, off, msk, bias, out);
}

// Round 4
// 93.330 us; speedup vs baseline: 1.5763x; 1.5763x over previous
//
#include <hip/hip_runtime.h>

#define BATCH 8
#define CIN   64
#define COUT  64
#define Hdim  128
#define Wdim  128
#define HW    (Hdim * Wdim)

typedef unsigned short ushort_t;
typedef unsigned short ushort8 __attribute__((ext_vector_type(8)));
typedef short short8 __attribute__((ext_vector_type(8)));
typedef unsigned int u32x4 __attribute__((ext_vector_type(4)));
typedef float f32x2 __attribute__((ext_vector_type(2)));
typedef float f32x4 __attribute__((ext_vector_type(4)));

__device__ __forceinline__ ushort_t f2b(float f) {
    unsigned int u = __float_as_uint(f);
    return (ushort_t)((u + 0x8000u) >> 16);
}
__device__ __forceinline__ f32x2 unpk(unsigned int u) {
    f32x2 v;
    v.x = __uint_as_float(u << 16);
    v.y = __uint_as_float(u & 0xffff0000u);
    return v;
}
__device__ __forceinline__ unsigned int pack2(f32x2 v) {
    unsigned int lo = (__float_as_uint(v.x) + 0x8000u) >> 16;
    unsigned int hi = (__float_as_uint(v.y) + 0x8000u) & 0xffff0000u;
    return lo | hi;
}

// ---------------- prep: x (B,C,H,W) f32 -> xt (B,H,W,C) bf16 ; w (O,C,3,3) f32 -> wt (9,O,C) bf16
__global__ __launch_bounds__(256) void dcnv2_prep(
    const float* __restrict__ x, const float* __restrict__ w,
    ushort_t* __restrict__ xt, ushort_t* __restrict__ wt)
{
    int bid = blockIdx.x;
    if (bid < 4096) {
        int g = bid * 256 + threadIdx.x;          // B*HW*8 = 1,048,576
        int pixel = g >> 3;
        int c0 = (g & 7) << 3;
        int b = pixel >> 14, hw = pixel & (HW - 1);
        const float* xp = x + (size_t)(b * CIN + c0) * HW + hw;
        ushort8 o;
#pragma unroll
        for (int i = 0; i < 8; ++i) o[i] = f2b(xp[(size_t)i * HW]);
        *(ushort8*)(xt + (size_t)pixel * 64 + c0) = o;
    } else {
        int t2 = (bid - 4096) * 256 + threadIdx.x; // 0..4095
        int o = t2 >> 6, c = t2 & 63;
        const float* wp = w + (size_t)(o * 64 + c) * 9;
#pragma unroll
        for (int k = 0; k < 9; ++k) wt[k * 4096 + o * 64 + c] = f2b(wp[k]);
    }
}

// ---- gather: 4 bilinear corners x 16 channels (8 x 16B loads) + weights
struct Gather {
    u32x4 a00, b00, a01, b01, a10, b10, a11, b11;
    float w00, w01, w10, w11;
};

__device__ __forceinline__ Gather gather16(
    const ushort_t* __restrict__ xtb, int c0, int y, int xq,
    int ky, int kx, float oyk, float oxk, float mk)
{
    Gather g;
    float py = (float)(y - 1 + ky) + oyk;
    float px = (float)(xq - 1 + kx) + oxk;
    float fy = floorf(py), fx = floorf(px);
    float ly = py - fy, lx = px - fx;
    float hy = 1.f - ly, hx = 1.f - lx;
    int y0 = (int)fy, x0 = (int)fx;
    int y1 = y0 + 1, x1 = x0 + 1;
    float vy0 = (y0 >= 0 && y0 < Hdim) ? mk : 0.f;
    float vy1 = (y1 >= 0 && y1 < Hdim) ? mk : 0.f;
    float vx0 = (x0 >= 0 && x0 < Wdim) ? 1.f : 0.f;
    float vx1 = (x1 >= 0 && x1 < Wdim) ? 1.f : 0.f;
    g.w00 = hy * hx * vy0 * vx0;
    g.w01 = hy * lx * vy0 * vx1;
    g.w10 = ly * hx * vy1 * vx0;
    g.w11 = ly * lx * vy1 * vx1;
    int cy0 = min(max(y0, 0), Hdim - 1), cy1 = min(max(y1, 0), Hdim - 1);
    int cx0 = min(max(x0, 0), Wdim - 1), cx1 = min(max(x1, 0), Wdim - 1);
    const ushort_t* p00 = xtb + (((cy0 << 7) + cx0) << 6) + c0;
    const ushort_t* p01 = xtb + (((cy0 << 7) + cx1) << 6) + c0;
    const ushort_t* p10 = xtb + (((cy1 << 7) + cx0) << 6) + c0;
    const ushort_t* p11 = xtb + (((cy1 << 7) + cx1) << 6) + c0;
    g.a00 = *(const u32x4*)p00; g.b00 = *(const u32x4*)(p00 + 8);
    g.a01 = *(const u32x4*)p01; g.b01 = *(const u32x4*)(p01 + 8);
    g.a10 = *(const u32x4*)p10; g.b10 = *(const u32x4*)(p10 + 8);
    g.a11 = *(const u32x4*)p11; g.b11 = *(const u32x4*)(p11 + 8);
    return g;
}

__device__ __forceinline__ void blend16(const Gather& g, u32x4& olo, u32x4& ohi) {
#pragma unroll
    for (int i = 0; i < 4; ++i) {
        f32x2 v = unpk(g.a00[i]) * g.w00;
        v += unpk(g.a01[i]) * g.w01;
        v += unpk(g.a10[i]) * g.w10;
        v += unpk(g.a11[i]) * g.w11;
        olo[i] = pack2(v);
        f32x2 u = unpk(g.b00[i]) * g.w00;
        u += unpk(g.b01[i]) * g.w01;
        u += unpk(g.b10[i]) * g.w10;
        u += unpk(g.b11[i]) * g.w11;
        ohi[i] = pack2(u);
    }
}

// ---------------- main: fused deformable-im2col + bf16 MFMA GEMM
// 256 thr (4 waves), 64 px/block. col AND wl double-buffered + XOR-chunk-
// swizzled (conflict-free). ONE barrier per tap; tap k+1's gathers and W
// loads issue BEFORE tap k's MFMA (async-stage), blend + LDS writes after.
__global__ __launch_bounds__(256) void dcnv2_mfma(
    const ushort_t* __restrict__ xt,   // (B,H,W,C) bf16
    const ushort_t* __restrict__ wt,   // (9,O,C) bf16
    const float* __restrict__ off,     // (B,18,H,W)
    const float* __restrict__ msk,     // (B,9,H,W)
    const float* __restrict__ bias,    // (O)
    float* __restrict__ out)           // (B,O,H,W)
{
    __shared__ ushort_t col[2][64 * 64];   // 2 x 8KB pixels
    __shared__ ushort_t wl [2][64 * 64];   // 2 x 8KB weights

    int bid = blockIdx.x;
    int swz = (bid & 7) * 256 + (bid >> 3);   // XCD swizzle (2048 % 8 == 0)
    int tid = threadIdx.x;
    int pbase = swz << 6;
    int lane = tid & 63;
    int wv = tid >> 6;

    // ---- sampling mapping: lane = pixel row, wave = 16-channel slice
    int p  = lane;
    int c0 = wv << 4;
    int pixel = pbase + p;
    int bb = pixel >> 14;
    int hw = pixel & (HW - 1);
    int y = hw >> 7, xq = hw & (Wdim - 1);

    const float* offb = off + (size_t)(bb * 18) * HW + hw;
    const float* mb   = msk + (size_t)(bb * 9) * HW + hw;
    const ushort_t* xtb = xt + ((size_t)bb << 20);

    // preload all offsets/mask (register arrays, fully unrolled)
    float oy[9], ox[9], mm[9];
#pragma unroll
    for (int k = 0; k < 9; ++k) {
        oy[k] = offb[(size_t)(2 * k)     * HW];
        ox[k] = offb[(size_t)(2 * k + 1) * HW];
        mm[k] = mb  [(size_t)k * HW];
    }

    // col write positions (row p, chunks 2wv, 2wv+1, XOR-swizzled)
    int q = p & 7;
    int cp0 = (p << 6) + ((((wv << 1))     ^ q) << 3);
    int cp1 = (p << 6) + ((((wv << 1) | 1) ^ q) << 3);

    // W staging mapping: thread -> (o = tid>>2, chunks 2*(tid&3), +1)
    int ws_o  = tid >> 2;
    int ws_cb = (tid & 3) << 1;
    const ushort_t* wsrc = wt + ws_o * 64 + (ws_cb << 3);   // + k*4096
    int wp0 = (ws_o << 6) + (((ws_cb)     ^ (ws_o & 7)) << 3);
    int wp1 = (ws_o << 6) + (((ws_cb | 1) ^ (ws_o & 7)) << 3);

    // mfma mapping: wave wv owns pixel rows [wv*16,+16), all 64 outs
    int arow = (wv << 4) + (lane & 15);
    int asw  = arow & 7;
    int hi4  = lane >> 4;
    int bsw  = lane & 7;        // (n*16+(lane&15)) & 7 == lane & 7

    f32x4 acc[4];
#pragma unroll
    for (int n = 0; n < 4; ++n) acc[n] = (f32x4){0.f, 0.f, 0.f, 0.f};

    // ---- prologue: fill buffer 0 with tap 0
    {
        Gather g = gather16(xtb, c0, y, xq, 0, 0, oy[0], ox[0], mm[0]);
        u32x4 wr0 = *(const u32x4*)(wsrc);
        u32x4 wr1 = *(const u32x4*)(wsrc + 8);
        u32x4 olo, ohi;
        blend16(g, olo, ohi);
        *(u32x4*)(&col[0][cp0]) = olo;
        *(u32x4*)(&col[0][cp1]) = ohi;
        *(u32x4*)(&wl [0][wp0]) = wr0;
        *(u32x4*)(&wl [0][wp1]) = wr1;
    }
    __syncthreads();

#pragma unroll
    for (int k = 0; k < 9; ++k) {
        Gather g;
        u32x4 wr0, wr1;
        if (k < 8) {
            const int kp = k + 1;
            const int ky = kp / 3, kx = kp % 3;
            // issue next tap's global loads EARLY (hide under MFMA below)
            g = gather16(xtb, c0, y, xq, ky, kx, oy[kp], ox[kp], mm[kp]);
            wr0 = *(const u32x4*)(wsrc + kp * 4096);
            wr1 = *(const u32x4*)(wsrc + kp * 4096 + 8);
        }

        // ---- MFMA tap k: K=64 (2 k-steps of 32), A/B from swizzled LDS
        const ushort_t* cb = &col[k & 1][0];
        const ushort_t* wb = &wl [k & 1][0];
#pragma unroll
        for (int s = 0; s < 2; ++s) {
            int chA = ((s << 2) + hi4) ^ asw;
            short8 af = *(const short8*)(cb + (arow << 6) + (chA << 3));
            int chB = ((s << 2) + hi4) ^ bsw;
#pragma unroll
            for (int n = 0; n < 4; ++n) {
                int brow = (n << 4) + (lane & 15);
                short8 bf = *(const short8*)(wb + (brow << 6) + (chB << 3));
                acc[n] = __builtin_amdgcn_mfma_f32_16x16x32_bf16(af, bf, acc[n], 0, 0, 0);
            }
        }

        if (k < 8) {
            u32x4 olo, ohi;
            blend16(g, olo, ohi);
            ushort_t* cw = &col[(k + 1) & 1][0];
            ushort_t* ww = &wl [(k + 1) & 1][0];
            *(u32x4*)(cw + cp0) = olo;
            *(u32x4*)(cw + cp1) = ohi;
            *(u32x4*)(ww + wp0) = wr0;
            *(u32x4*)(ww + wp1) = wr1;
            __syncthreads();
        }
    }

    // ---- epilogue: D row = pixel (lane>>4)*4+j, col = out (lane&15)
    int hwb = pbase & (HW - 1);
    float* ob = out + ((size_t)bb << 6) * HW;
#pragma unroll
    for (int n = 0; n < 4; ++n) {
        int o = n * 16 + (lane & 15);
        float bv = bias[o];
#pragma unroll
        for (int j = 0; j < 4; ++j) {
            int ploc = (wv << 4) + (hi4 << 2) + j;
            ob[((size_t)o << 14) + hwb + ploc] = acc[n][j] + bv;
        }
    }
}

// ---------------- fallback (direct fp32 kernel) if ws too small
__global__ __launch_bounds__(256) void dcnv2_direct(
    const float* __restrict__ x, const float* __restrict__ off,
    const float* __restrict__ msk, const float* __restrict__ wgt,
    const float* __restrict__ bias, float* __restrict__ out)
{
    int pg = blockIdx.x * 256 + threadIdx.x;
    int b = pg >> 14;
    int hw = pg & (HW - 1);
    int y = hw >> 7;
    int xq = hw & (Wdim - 1);
    float acc[COUT];
#pragma unroll
    for (int o = 0; o < COUT; ++o) acc[o] = 0.0f;
    const float* xb = x + b * CIN * HW;
    const float* offb = off + b * 18 * HW + hw;
    const float* mb = msk + b * 9 * HW + hw;
    for (int k = 0; k < 9; ++k) {
        int ky = k / 3, kx = k % 3;
        float py = (float)(y - 1 + ky) + offb[(2 * k) * HW];
        float px = (float)(xq - 1 + kx) + offb[(2 * k + 1) * HW];
        float m = mb[k * HW];
        float fy = floorf(py), fx = floorf(px);
        float ly = py - fy, lx = px - fx;
        float hy = 1.0f - ly, hx = 1.0f - lx;
        int y0 = (int)fy, x0 = (int)fx;
        int y1 = y0 + 1, x1 = x0 + 1;
        float vy0 = (y0 >= 0 && y0 < Hdim) ? 1.f : 0.f;
        float vy1 = (y1 >= 0 && y1 < Hdim) ? 1.f : 0.f;
        float vx0 = (x0 >= 0 && x0 < Wdim) ? 1.f : 0.f;
        float vx1 = (x1 >= 0 && x1 < Wdim) ? 1.f : 0.f;
        float w00 = hy * hx * vy0 * vx0 * m, w01 = hy * lx * vy0 * vx1 * m;
        float w10 = ly * hx * vy1 * vx0 * m, w11 = ly * lx * vy1 * vx1 * m;
        int cy0 = min(max(y0, 0), Hdim - 1), cy1 = min(max(y1, 0), Hdim - 1);
        int cx0 = min(max(x0, 0), Wdim - 1), cx1 = min(max(x1, 0), Wdim - 1);
        int i00 = cy0 * Wdim + cx0, i01 = cy0 * Wdim + cx1;
        int i10 = cy1 * Wdim + cx0, i11 = cy1 * Wdim + cx1;
        const float* wk = wgt + k;
        const float* xc = xb;
        for (int c = 0; c < CIN; ++c) {
            float val = w00 * xc[i00] + w01 * xc[i01] + w10 * xc[i10] + w11 * xc[i11];
            const float* wc = wk + c * 9;
#pragma unroll
            for (int o = 0; o < COUT; ++o)
                acc[o] = fmaf(wc[o * (CIN * 9)], val, acc[o]);
            xc += HW;
        }
    }
    float* op = out + b * COUT * HW + hw;
#pragma unroll
    for (int o = 0; o < COUT; ++o) op[o * HW] = acc[o] + bias[o];
}

extern "C" void kernel_launch(void* const* d_in, const int* in_sizes, int n_in,
                              void* d_out, int out_size, void* d_ws, size_t ws_size,
                              hipStream_t stream) {
    const float* x    = (const float*)d_in[0];
    const float* off  = (const float*)d_in[1];
    const float* msk  = (const float*)d_in[2];
    const float* wgt  = (const float*)d_in[3];
    const float* bias = (const float*)d_in[4];
    float* out = (float*)d_out;

    const size_t xt_elems = (size_t)BATCH * HW * 64;   // 8,388,608 bf16
    const size_t wt_elems = 9 * 4096;                  // 36,864 bf16
    const size_t need = (xt_elems + wt_elems) * sizeof(ushort_t);

    if (ws_size < need) {
        dcnv2_direct<<<(BATCH * HW) / 256, 256, 0, stream>>>(x, off, msk, wgt, bias, out);
        return;
    }

    ushort_t* xt = (ushort_t*)d_ws;
    ushort_t* wt = xt + xt_elems;

    dcnv2_prep<<<4096 + 16, 256, 0, stream>>>(x, wgt, xt, wt);
    dcnv2_mfma<<<2048, 256, 0, stream>>>(xt, wt, off, msk, bias, out);
}